// Round 7
// baseline (663.216 us; speedup 1.0000x reference)
//
#include <hip/hip_runtime.h>
#include <math.h>

// StackedLSTM: B=2048, T=2048, D=H=6, 2 layers, softmax(h_last) -> [2048, 6] fp32.
//
// R6 structure (best so far, 586us, VALU-issue-bound at 1 wave/SIMD):
//   each 16-lane DPP row = a self-contained 2-layer LSTM for ONE batch.
//   lane-in-row = 2j+p (unit j=0..5, pair p; lanes 12-15 pad); each lane runs
//   both layers' (A,B) gate rows: A = i(p=0)/g(p=1), B = f/o.  Layer 1 runs
//   one timestep behind layer 0.  Wave = 4 rows: rows 0,1 = batches 2b,2b+1;
//   rows 2,3 mirror.  All cross-lane traffic is intra-row DPP (VALU pipe):
//   h gather = quad_perm bcast (0x00/0xAA) + row_ror:4/8/12 -> 8 slots
//   (rotation semantics probed at init; weights loaded in arrival order);
//   (i,f)<->(g,o) exchange = quad_perm(1,0,3,2).
//
// R7 change: dot products in PACKED FP32.  R6 rocprof: 491 issue cyc/step of
//   686 total; 120 of those are 60 scalar v_fma.  The gather slots are natural
//   (even,odd) pairs and x arrives as float2, so all dots become
//   ext_vector(2) fma -> v_pk_fma_f32 (MI355X packed-fp32, 2x rate):
//   60 fma -> 30 pk_fma, and the per-acc chain depth halves (3-4 deep).

#define TSTEPS 2048
#define LOG2E 1.442695040889f

typedef float v2f __attribute__((ext_vector_type(2)));

__device__ __forceinline__ float fast_rcp(float v) { return __builtin_amdgcn_rcpf(v); }

#if __has_builtin(__builtin_amdgcn_exp2f)
#define EXP2F(x) __builtin_amdgcn_exp2f(x)
#else
#define EXP2F(x) __expf((x) * 0.69314718056f)
#endif

#define DPPI(v, CTRL) __builtin_amdgcn_mov_dpp((v), (CTRL), 0xF, 0xF, true)
#define DPPF(v, CTRL) __int_as_float(DPPI(__float_as_int(v), (CTRL)))

#define PKFMA(a, b, c) __builtin_elementwise_fma((a), (b), (c))

// 8-slot intra-row gather as 4 (even-unit, odd-unit) v2f pairs:
// pair 0 = quad bcasts (lane0, lane2); pairs 1..3 = row_ror 4/8/12 of pair 0.
#define GATHER8PK(dst, src)                                                 \
    {                                                                       \
        const float _dA = DPPF((src), 0x00);                                \
        const float _dB = DPPF((src), 0xAA);                                \
        dst[0] = (v2f){_dA, _dB};                                           \
        dst[1] = (v2f){DPPF(_dA, 0x124), DPPF(_dB, 0x124)};                 \
        dst[2] = (v2f){DPPF(_dA, 0x128), DPPF(_dB, 0x128)};                 \
        dst[3] = (v2f){DPPF(_dA, 0x12C), DPPF(_dB, 0x12C)};                 \
    }

__global__ __launch_bounds__(64, 1)
void stacked_lstm_kernel(const float* __restrict__ x,
                         const float* __restrict__ Wih0, const float* __restrict__ Whh0,
                         const float* __restrict__ bih0, const float* __restrict__ bhh0,
                         const float* __restrict__ Wih1, const float* __restrict__ Whh1,
                         const float* __restrict__ bih1, const float* __restrict__ bhh1,
                         float* __restrict__ out)
{
    const int lane = threadIdx.x;
    const int rl  = lane & 15;            // lane within 16-lane row
    const int row = (lane >> 4) & 1;      // rows 2,3 mirror rows 0,1
    const int j  = rl >> 1;               // unit 0..7 (6,7 pad)
    const int p  = rl & 1;                // 0 -> (i,f) rows; 1 -> (g,o) rows
    const int uc = (j < 6) ? j : 5;
    const long b = (long)blockIdx.x * 2 + row;

    // ---- probe the gather tree with unit ids (immune to ror semantics) ----
    int ids[8];
    {
        const int idv = (rl < 12) ? j : 6;   // pad quad marked >=6
        const int dA = DPPI(idv, 0x00);
        const int dB = DPPI(idv, 0xAA);
        ids[0] = dA;               ids[1] = dB;
        ids[2] = DPPI(dA, 0x124);  ids[3] = DPPI(dB, 0x124);
        ids[4] = DPPI(dA, 0x128);  ids[5] = DPPI(dB, 0x128);
        ids[6] = DPPI(dA, 0x12C);  ids[7] = DPPI(dB, 0x12C);
    }

    // ---- per-lane weights, exp2-domain scale folded in, arrival-ordered ----
    // PyTorch gate rows: i=0..5, f=6..11, g=12..17, o=18..23
    const int rA = p * 12 + uc;           // p=0: i-row ; p=1: g-row
    const int rB = rA + 6;                // p=0: f-row ; p=1: o-row
    // sigmoid(v)=rcp(1+exp2(-L v)); tanh(v)=2*rcp(1+exp2(-2L v))-1
    const float scA = p ? (-2.0f * LOG2E) : (-LOG2E);
    const float scB = -LOG2E;
    const float cAc = p ? 2.0f : 1.0f;
    const float dAc = p ? -1.0f : 0.0f;

    v2f WxA[3], WxB[3];                   // L0 x-term (natural pair order)
#pragma unroll
    for (int k = 0; k < 3; ++k) {
        WxA[k] = (v2f){Wih0[rA * 6 + 2 * k] * scA, Wih0[rA * 6 + 2 * k + 1] * scA};
        WxB[k] = (v2f){Wih0[rB * 6 + 2 * k] * scB, Wih0[rB * 6 + 2 * k + 1] * scB};
    }
    // gather-order weights as v2f pairs (slots 2s, 2s+1)
    v2f WhA0[4], WhB0[4], WiA1[4], WiB1[4], WhA1[4], WhB1[4];
#pragma unroll
    for (int s = 0; s < 4; ++s) {
        const int i0 = ids[2 * s], i1 = ids[2 * s + 1];
        const bool k0 = (i0 >= 0) && (i0 < 6), k1 = (i1 >= 0) && (i1 < 6);
        WhA0[s] = (v2f){k0 ? Whh0[rA * 6 + i0] * scA : 0.0f,
                        k1 ? Whh0[rA * 6 + i1] * scA : 0.0f};
        WhB0[s] = (v2f){k0 ? Whh0[rB * 6 + i0] * scB : 0.0f,
                        k1 ? Whh0[rB * 6 + i1] * scB : 0.0f};
        WiA1[s] = (v2f){k0 ? Wih1[rA * 6 + i0] * scA : 0.0f,
                        k1 ? Wih1[rA * 6 + i1] * scA : 0.0f};
        WiB1[s] = (v2f){k0 ? Wih1[rB * 6 + i0] * scB : 0.0f,
                        k1 ? Wih1[rB * 6 + i1] * scB : 0.0f};
        WhA1[s] = (v2f){k0 ? Whh1[rA * 6 + i0] * scA : 0.0f,
                        k1 ? Whh1[rA * 6 + i1] * scA : 0.0f};
        WhB1[s] = (v2f){k0 ? Whh1[rB * 6 + i0] * scB : 0.0f,
                        k1 ? Whh1[rB * 6 + i1] * scB : 0.0f};
    }
    const float bA0 = (bih0[rA] + bhh0[rA]) * scA;
    const float bB0 = (bih0[rB] + bhh0[rB]) * scB;
    const float bA1 = (bih1[rA] + bhh1[rA]) * scA;
    const float bB1 = (bih1[rB] + bhh1[rB]) * scB;

    // ---- x prefetch ring: 4 steps x 3 float2 in VGPRs ----
    const float* xb = x + b * (TSTEPS * 6);
    float2 xs0[3], xs1[3], xs2[3], xs3[3];
    {
        const float2* xp = (const float2*)xb;
        xs0[0] = xp[0];  xs0[1] = xp[1];  xs0[2] = xp[2];
        xs1[0] = xp[3];  xs1[1] = xp[4];  xs1[2] = xp[5];
        xs2[0] = xp[6];  xs2[1] = xp[7];  xs2[2] = xp[8];
        xs3[0] = xp[9];  xs3[1] = xp[10]; xs3[2] = xp[11];
    }

    float hv0 = 0.0f, c0 = 0.0f;   // layer-0 state of own unit (pair-duplicated)
    float hv1 = 0.0f, c1 = 0.0f;   // layer-1 state

#define STEP(XS, tp)                                                        \
    {                                                                       \
        v2f G0[4], G1[4];                                                   \
        GATHER8PK(G0, hv0)                                                  \
        GATHER8PK(G1, hv1)                                                  \
        const v2f XV0 = (v2f){XS[0].x, XS[0].y};                            \
        const v2f XV1 = (v2f){XS[1].x, XS[1].y};                            \
        const v2f XV2 = (v2f){XS[2].x, XS[2].y};                            \
        /* L0 rows: bias + dot(x) and dot(h0) in split pk accs */           \
        v2f aA0 = (v2f){bA0, 0.0f}, aB0 = (v2f){bB0, 0.0f};                 \
        aA0 = PKFMA(XV0, WxA[0], aA0); aB0 = PKFMA(XV0, WxB[0], aB0);       \
        aA0 = PKFMA(XV1, WxA[1], aA0); aB0 = PKFMA(XV1, WxB[1], aB0);       \
        aA0 = PKFMA(XV2, WxA[2], aA0); aB0 = PKFMA(XV2, WxB[2], aB0);       \
        v2f hA0 = G0[0] * WhA0[0], hB0 = G0[0] * WhB0[0];                   \
        /* L1 rows: bias + dot(h0) and dot(h1) in split pk accs */          \
        v2f aA1 = (v2f){bA1, 0.0f}, aB1 = (v2f){bB1, 0.0f};                 \
        v2f hA1 = G1[0] * WhA1[0], hB1 = G1[0] * WhB1[0];                   \
        aA1 = PKFMA(G0[0], WiA1[0], aA1); aB1 = PKFMA(G0[0], WiB1[0], aB1); \
        _Pragma("unroll")                                                   \
        for (int s = 1; s < 4; ++s) {                                       \
            hA0 = PKFMA(G0[s], WhA0[s], hA0);                               \
            hB0 = PKFMA(G0[s], WhB0[s], hB0);                               \
            aA1 = PKFMA(G0[s], WiA1[s], aA1);                               \
            aB1 = PKFMA(G0[s], WiB1[s], aB1);                               \
            hA1 = PKFMA(G1[s], WhA1[s], hA1);                               \
            hB1 = PKFMA(G1[s], WhB1[s], hB1);                               \
        }                                                                   \
        {   /* refill this ring slot with x[tp] (after consumption) */      \
            const float2* xq = (const float2*)(xb + (size_t)(tp) * 6);      \
            XS[0] = xq[0]; XS[1] = xq[1]; XS[2] = xq[2];                    \
        }                                                                   \
        const v2f mA0 = aA0 + hA0, mB0 = aB0 + hB0;                         \
        const v2f mA1 = aA1 + hA1, mB1 = aB1 + hB1;                         \
        const float sA0 = mA0.x + mA0.y, sB0 = mB0.x + mB0.y;               \
        const float sA1 = mA1.x + mA1.y, sB1 = mB1.x + mB1.y;               \
        /* layer 0 */                                                       \
        const float eA0 = EXP2F(sA0), eB0 = EXP2F(sB0);                     \
        const float aAc0 = fmaf(cAc, fast_rcp(1.0f + eA0), dAc);            \
        const float aBc0 = fast_rcp(1.0f + eB0);                            \
        const float xA0 = DPPF(aAc0, 0xB1), xB0 = DPPF(aBc0, 0xB1);         \
        const float ig0 = aAc0 * xA0;                                       \
        const float gf0 = p ? xB0 : aBc0;                                   \
        const float go0 = p ? aBc0 : xB0;                                   \
        const float cn0 = fmaf(gf0, c0, ig0);                               \
        const float t0e = EXP2F(cn0 * (-2.0f * LOG2E));                     \
        const float th0 = fmaf(2.0f, fast_rcp(1.0f + t0e), -1.0f);          \
        hv0 = go0 * th0; c0 = cn0;                                          \
        /* layer 1 (one step behind) */                                     \
        const float eA1 = EXP2F(sA1), eB1 = EXP2F(sB1);                     \
        const float aAc1 = fmaf(cAc, fast_rcp(1.0f + eA1), dAc);            \
        const float aBc1 = fast_rcp(1.0f + eB1);                            \
        const float xA1 = DPPF(aAc1, 0xB1), xB1 = DPPF(aBc1, 0xB1);         \
        const float ig1 = aAc1 * xA1;                                       \
        const float gf1 = p ? xB1 : aBc1;                                   \
        const float go1 = p ? aBc1 : xB1;                                   \
        const float cn1 = fmaf(gf1, c1, ig1);                               \
        const float t1e = EXP2F(cn1 * (-2.0f * LOG2E));                     \
        const float th1 = fmaf(2.0f, fast_rcp(1.0f + t1e), -1.0f);          \
        hv1 = go1 * th1; c1 = cn1;                                          \
    }

    // t = 0: layer 0 does step 0; layer 1 computes a phantom -> squash.
    STEP(xs0, 4)
    hv1 = 0.0f; c1 = 0.0f;

    // t = 1..2048 (at iter t: L0 does step t, L1 does step t-1).
    // Prefetch row t+4, clamped to 2047 (tail re-reads feed phantom L0 steps).
    for (int tb = 1; tb <= TSTEPS - 3; tb += 4) {
        const int p0 = (tb + 4 < TSTEPS) ? tb + 4 : TSTEPS - 1;
        const int p1 = (tb + 5 < TSTEPS) ? tb + 5 : TSTEPS - 1;
        const int p2 = (tb + 6 < TSTEPS) ? tb + 6 : TSTEPS - 1;
        const int p3 = (tb + 7 < TSTEPS) ? tb + 7 : TSTEPS - 1;
        STEP(xs1, p0)
        STEP(xs2, p1)
        STEP(xs3, p2)
        STEP(xs0, p3)
    }

    // ---- epilogue: hv1 = h1(T-1); per-lane softmax via one more gather ----
    float gf[8];
    {
        const float _dA = DPPF(hv1, 0x00);
        const float _dB = DPPF(hv1, 0xAA);
        gf[0] = _dA;               gf[1] = _dB;
        gf[2] = DPPF(_dA, 0x124);  gf[3] = DPPF(_dB, 0x124);
        gf[4] = DPPF(_dA, 0x128);  gf[5] = DPPF(_dB, 0x128);
        gf[6] = DPPF(_dA, 0x12C);  gf[7] = DPPF(_dB, 0x12C);
    }
    float mx = -3.0e38f;
#pragma unroll
    for (int s = 0; s < 8; ++s) {
        const float v = (ids[s] < 6) ? gf[s] : -3.0e38f;
        mx = fmaxf(mx, v);
    }
    float sum = 0.0f;
#pragma unroll
    for (int s = 0; s < 8; ++s) {
        const float e = (ids[s] < 6) ? __expf(gf[s] - mx) : 0.0f;
        sum += e;
    }
    const float rs = fast_rcp(sum);
    if (p == 0 && j < 6 && lane < 32) {
        out[b * 6 + j] = __expf(hv1 - mx) * rs;
    }
}

extern "C" void kernel_launch(void* const* d_in, const int* in_sizes, int n_in,
                              void* d_out, int out_size, void* d_ws, size_t ws_size,
                              hipStream_t stream) {
    (void)in_sizes; (void)n_in; (void)d_ws; (void)ws_size; (void)out_size;
    const float* x    = (const float*)d_in[0];
    const float* Wih0 = (const float*)d_in[1];
    const float* Whh0 = (const float*)d_in[2];
    const float* bih0 = (const float*)d_in[3];
    const float* bhh0 = (const float*)d_in[4];
    const float* Wih1 = (const float*)d_in[5];
    const float* Whh1 = (const float*)d_in[6];
    const float* bih1 = (const float*)d_in[7];
    const float* bhh1 = (const float*)d_in[8];
    float* outp = (float*)d_out;

    // 2 batches per wave (rows 0,1; rows 2,3 mirror): 1024 blocks x 64 threads
    // = 1024 waves = 1 wave per SIMD machine-wide.
    stacked_lstm_kernel<<<1024, 64, 0, stream>>>(
        x, Wih0, Whh0, bih0, bhh0, Wih1, Whh1, bih1, bhh1, outp);
}